// Round 1
// 215.083 us; speedup vs baseline: 1.0124x; 1.0124x over previous
//
#include <hip/hip_runtime.h>

#define T_MAX 512
#define BATCH 32
#define CLASSES 1296
#define L_MAX 64
#define NROWS (T_MAX * BATCH)   // 16384
#define NINF (-INFINITY)
#define COLSTRIDE (BATCH * CLASSES)   // floats between consecutive time steps

// DPP wave64 sum: row_shr 1/2/4/8 + row_bcast 15/31. Total lands in LANE 63.
__device__ __forceinline__ float wave_sum64(float v) {
    v += __int_as_float(__builtin_amdgcn_update_dpp(0, __float_as_int(v), 0x111, 0xF, 0xF, true));
    v += __int_as_float(__builtin_amdgcn_update_dpp(0, __float_as_int(v), 0x112, 0xF, 0xF, true));
    v += __int_as_float(__builtin_amdgcn_update_dpp(0, __float_as_int(v), 0x114, 0xF, 0xF, true));
    v += __int_as_float(__builtin_amdgcn_update_dpp(0, __float_as_int(v), 0x118, 0xF, 0xF, true));
    v += __int_as_float(__builtin_amdgcn_update_dpp(0, __float_as_int(v), 0x142, 0xF, 0xF, true));
    v += __int_as_float(__builtin_amdgcn_update_dpp(0, __float_as_int(v), 0x143, 0xF, 0xF, true));
    return v;
}

// ---------------------------------------------------------------------------
// MEGA kernel: everything that has no inter-dependency runs concurrently.
//   blocks 0..31          : align DP for batch b (register gather from seq_pred
//                           -- the DP is invariant to the log-softmax shift, so
//                           raw logits work; no pb intermediate, no K1 dep)
//   blocks 32..4127       : seq_pred rowstats -> lse_seq
//   blocks 4128..8223     : pred rowstats -> lse_pred, sum_pred
// The 8192 streaming blocks (128 MB) hide the 32 serial DP waves' latency.
// ---------------------------------------------------------------------------
__global__ __launch_bounds__(256) void mega_kernel(
    const float* __restrict__ pred, const float* __restrict__ seqp,
    const int* __restrict__ label, const int* __restrict__ x_len,
    const int* __restrict__ label_len,
    float* __restrict__ lse_pred, float* __restrict__ sum_pred,
    float* __restrict__ lse_seq, int* __restrict__ tg,
    int* __restrict__ counter)
{
    __shared__ unsigned chw[1024];   // [panel 0..15][lane] choice bits (4 KB)
    __shared__ int a_s[64];
    __shared__ int rows_s[T_MAX];

    if (blockIdx.x < 32) {
        // ---------------- align path: one wave, register-gather fed ----------------
        if (threadIdx.x >= 64) return;
        const int b = blockIdx.x, lane = threadIdx.x;
        if (b == 0 && lane == 0) *counter = 0;
        const int C = x_len[b], R = label_len[b];
        const int limit = C - R;
        const int lab = label[(b << 6) + lane];
        const float* gsrc = seqp + (size_t)b * CLASSES + lab;  // + t*COLSTRIDE walks time
        const int P = (C + 31) >> 5;
        const float biasR = (lane < R) ? 0.f : NINF;
        const bool isb0 = (lane & 15) == 0;
        const int ninf_i = 0xFF800000;

        float va[32], vb[32];
        float dp = NINF;

#define LOAD_PANEL(VV, LDP) {                                                  \
        const float* s_ = gsrc + (size_t)(LDP) * 32 * COLSTRIDE;               \
        _Pragma("unroll")                                                      \
        for (int u = 0; u < 32; ++u) VV[u] = s_[(size_t)u * COLSTRIDE];        \
    }

#define COMPUTE_PANEL(VV, PP) {                                                \
        const int base = (PP) << 5;                                            \
        unsigned w0 = 0;                                                       \
        _Pragma("unroll")                                                      \
        for (int g = 0; g < 2; ++g) {                                          \
            const bool general = ((PP) == 0) || (base + (g << 4) + 15 > limit);\
            _Pragma("unroll")                                                  \
            for (int u = 0; u < 16; ++u) {                                     \
                const int kk = (g << 4) + u;                                   \
                const int j = base + kk;                                       \
                float val;                                                     \
                if (general) {                                                 \
                    if ((PP) == 0 && kk == 0) {          /* column 0 init */   \
                        dp = (lane == 0) ? VV[0] : NINF;                       \
                        continue;                                              \
                    }                                                          \
                    const bool ib = (lane <= j) && (lane >= j - limit) && (lane < R); \
                    val = ib ? VV[kk] : NINF;                                  \
                } else {                                                       \
                    val = VV[kk] + biasR;                 /* off-chain R mask */ \
                }                                                              \
                const int dpb = __float_as_int(dp);                            \
                const int t1 = __builtin_amdgcn_update_dpp(ninf_i, dpb, 0x111, 0xF, 0xF, false); /* row_shr:1 */ \
                const int t2 = __builtin_amdgcn_update_dpp(ninf_i, dpb, 0x142, 0xF, 0xF, false); /* row_bcast15 */ \
                const float shifted = __int_as_float(isb0 ? t2 : t1);          \
                const bool c = shifted > dp;              /* strict, off chain */ \
                w0 |= (c ? 1u : 0u) << kk;                                     \
                dp = fmaxf(shifted, dp) + val;            /* == reference select */ \
            }                                                                  \
        }                                                                      \
        chw[((PP) << 6) + lane] = w0;                                          \
    }

        // software-pipelined: gather panel p+1 to regs while computing panel p
        LOAD_PANEL(va, 0)
        for (int p = 0; p < P; p += 2) {
            int l1 = p + 1; if (l1 >= P) l1 = P - 1;
            LOAD_PANEL(vb, l1)
            COMPUTE_PANEL(va, p)
            if (p + 1 >= P) break;
            int l2 = p + 2; if (l2 >= P) l2 = P - 1;
            LOAD_PANEL(va, l2)
            COMPUTE_PANEL(vb, p + 1)
        }
#undef LOAD_PANEL
#undef COMPUTE_PANEL

        // backtrack: per-row jumps via highest set bit in cached words
        if (lane == 0) {
            int row = R - 1, j = C - 1;
            while (row > 0 && j >= 0) {
                unsigned word = chw[((j >> 5) << 6) + row];
                unsigned mb = (2u << (j & 31)) - 1;
                unsigned m = word & mb;
                if (m) {
                    int hb = 31 - __clz(m);
                    int aj = (j & ~31) | hb;
                    a_s[row] = aj;
                    row--; j = aj - 1;
                } else {
                    j = (j & ~31) - 1;
                }
            }
            for (int i = row; i >= 0; --i) a_s[i] = 0;
        }
        // parallel interval fill: row i occupies [a_s[i], b_i]
        if (lane < R) {
            int a = a_s[lane];
            int bi = (lane == R - 1) ? (C - 1) : (a_s[lane + 1] - 1);
            for (int j = a; j <= bi; ++j) rows_s[j] = lane;
        }
        for (int j = lane; j < T_MAX; j += 64)
            tg[(b << 9) + j] = (j < C) ? rows_s[j] : -1;
    } else if (blockIdx.x < 32 + NROWS / 4) {
        // ---------------- seq_pred rowstats: one wave per row ----------------
        int r = (blockIdx.x - 32) * 4 + (threadIdx.x >> 6);
        int lane = threadIdx.x & 63;
        const float* xs = seqp + (size_t)r * CLASSES;
        const float4* s4 = (const float4*)xs;

        float4 b0 = s4[lane],       b1 = s4[lane + 64],  b2 = s4[lane + 128];
        float4 b3 = s4[lane + 192], b4 = s4[lane + 256];
        float4 bt = make_float4(0.f, 0.f, 0.f, 0.f);
        if (lane < 4) bt = s4[320 + lane];

        float ss = __expf(b0.x) + __expf(b0.y) + __expf(b0.z) + __expf(b0.w)
                 + __expf(b1.x) + __expf(b1.y) + __expf(b1.z) + __expf(b1.w)
                 + __expf(b2.x) + __expf(b2.y) + __expf(b2.z) + __expf(b2.w)
                 + __expf(b3.x) + __expf(b3.y) + __expf(b3.z) + __expf(b3.w)
                 + __expf(b4.x) + __expf(b4.y) + __expf(b4.z) + __expf(b4.w);
        if (lane < 4)
            ss += __expf(bt.x) + __expf(bt.y) + __expf(bt.z) + __expf(bt.w);
        ss = wave_sum64(ss);
        if (lane == 63) lse_seq[r] = __logf(ss);
    } else {
        // ---------------- pred rowstats: one wave per row ----------------
        int r = (blockIdx.x - (32 + NROWS / 4)) * 4 + (threadIdx.x >> 6);
        int lane = threadIdx.x & 63;
        const float* xp = pred + (size_t)r * CLASSES;
        const float4* p4 = (const float4*)xp;

        float4 a0 = p4[lane],       a1 = p4[lane + 64],  a2 = p4[lane + 128];
        float4 a3 = p4[lane + 192], a4 = p4[lane + 256];
        float4 at = make_float4(0.f, 0.f, 0.f, 0.f);
        if (lane < 4) at = p4[320 + lane];

        float sp = __expf(a0.x) + __expf(a0.y) + __expf(a0.z) + __expf(a0.w)
                 + __expf(a1.x) + __expf(a1.y) + __expf(a1.z) + __expf(a1.w)
                 + __expf(a2.x) + __expf(a2.y) + __expf(a2.z) + __expf(a2.w)
                 + __expf(a3.x) + __expf(a3.y) + __expf(a3.z) + __expf(a3.w)
                 + __expf(a4.x) + __expf(a4.y) + __expf(a4.z) + __expf(a4.w);
        float sx = (a0.x + a0.y + a0.z + a0.w) + (a1.x + a1.y + a1.z + a1.w)
                 + (a2.x + a2.y + a2.z + a2.w) + (a3.x + a3.y + a3.z + a3.w)
                 + (a4.x + a4.y + a4.z + a4.w);
        if (lane < 4) {
            sp += __expf(at.x) + __expf(at.y) + __expf(at.z) + __expf(at.w);
            sx += at.x + at.y + at.z + at.w;
        }
        sp = wave_sum64(sp);
        sx = wave_sum64(sx);
        if (lane == 63) {
            lse_pred[r] = __logf(sp);
            sum_pred[r] = sx;
        }
    }
}

// ---------------------------------------------------------------------------
// K2: per-element CE + fused last-block final reduction (agent-scope atomics).
// conf now gathered directly from seq_pred (pb intermediate removed).
// ---------------------------------------------------------------------------
__global__ __launch_bounds__(256) void ce_kernel(
    const float* __restrict__ pred, const float* __restrict__ seqp,
    const int* __restrict__ label, const int* __restrict__ x_len,
    const float* __restrict__ lse_pred, const float* __restrict__ sum_pred,
    const float* __restrict__ lse_seq,
    const int* __restrict__ tg, float* __restrict__ partials,
    int* __restrict__ counter, float* __restrict__ out)
{
    int e = blockIdx.x * 256 + threadIdx.x;    // e = t*BATCH + b
    int t = e >> 5, b = e & 31;
    float ce = 0.f;
    if (t < x_len[b]) {
        int row = tg[(b << 9) + t];
        int tgt = label[(b << 6) + row];
        float lp = lse_pred[e];
        float S = sum_pred[e] - (float)CLASSES * lp;        // sum_v log_softmax(pred)
        float lsp_t = pred[(size_t)e * CLASSES + tgt] - lp;
        float conf = __expf(seqp[(size_t)e * CLASSES + tgt] - lse_seq[e]);
        float smooth = (1.f - conf) * (1.f / (float)(CLASSES - 1));
        ce = -((conf - smooth) * lsp_t + smooth * S);
    }
    ce = wave_sum64(ce);                        // total in lane 63
    __shared__ float sm[4];
    __shared__ int amLast;
    if ((threadIdx.x & 63) == 63) sm[threadIdx.x >> 6] = ce;
    __syncthreads();
    if (threadIdx.x == 0) {
        float p = sm[0] + sm[1] + sm[2] + sm[3];
        __hip_atomic_store(&partials[blockIdx.x], p, __ATOMIC_RELEASE, __HIP_MEMORY_SCOPE_AGENT);
        amLast = (__hip_atomic_fetch_add(counter, 1, __ATOMIC_ACQ_REL, __HIP_MEMORY_SCOPE_AGENT) == 63);
    }
    __syncthreads();
    if (amLast && threadIdx.x < 64) {
        float v = __hip_atomic_load(&partials[threadIdx.x], __ATOMIC_ACQUIRE, __HIP_MEMORY_SCOPE_AGENT);
        for (int o = 32; o; o >>= 1) v += __shfl_down(v, o, 64);
        if (threadIdx.x == 0) out[0] = v * (1.0f / (float)NROWS);
    }
}

extern "C" void kernel_launch(void* const* d_in, const int* in_sizes, int n_in,
                              void* d_out, int out_size, void* d_ws, size_t ws_size,
                              hipStream_t stream) {
    const float* pred      = (const float*)d_in[0];
    const float* seq_pred  = (const float*)d_in[1];
    const int*   label     = (const int*)d_in[2];
    const int*   x_len     = (const int*)d_in[3];
    const int*   label_len = (const int*)d_in[4];
    float* out = (float*)d_out;

    // workspace layout (floats)
    float* w = (float*)d_ws;
    float* lse_pred = w;                       // 16384
    float* sum_pred = w + NROWS;               // 16384
    float* lse_seq  = w + 2 * NROWS;           // 16384
    int*   tg       = (int*)(w + 3 * NROWS);   // 16384 ints
    float* partials = (float*)(tg + NROWS);    // 64
    int*   counter  = (int*)(partials + 64);   // 1

    mega_kernel<<<32 + NROWS / 2, 256, 0, stream>>>(pred, seq_pred, label,
                                                    x_len, label_len,
                                                    lse_pred, sum_pred, lse_seq,
                                                    tg, counter);
    ce_kernel<<<64, 256, 0, stream>>>(pred, seq_pred, label, x_len,
                                      lse_pred, sum_pred, lse_seq, tg,
                                      partials, counter, out);
}